// Round 5
// baseline (244.338 us; speedup 1.0000x reference)
//
#include <hip/hip_runtime.h>
#include <stdint.h>
#include <stddef.h>

#define DIM   256
#define NH    8
#define HD    32
#define BATCH 16
#define NTOK  4096   // 64*64

typedef __attribute__((ext_vector_type(8))) short short8;
typedef __attribute__((ext_vector_type(4))) float f32x4;

__device__ __forceinline__ unsigned short f2bf(float x){
  unsigned u = __float_as_uint(x);
  u += 0x7fffu + ((u >> 16) & 1u);       // RNE
  return (unsigned short)(u >> 16);
}
__device__ __forceinline__ float elu1(float v){
  return (v > 0.f) ? (v + 1.f) : __expf(v);
}
// async global->LDS, 16B per lane. lds dest = wave-uniform base + lane*16.
__device__ __forceinline__ void gload_lds16(const void* g, void* lds){
  __builtin_amdgcn_global_load_lds(
      (const __attribute__((address_space(1))) unsigned int*)g,
      (__attribute__((address_space(3))) unsigned int*)lds, 16, 0, 0);
}

// ---------------- P1: x [b][c][n] f32 -> x_t [b][n][c] bf16 ----------------
__global__ __launch_bounds__(256) void k_transpose_x(const float* __restrict__ x,
                                                     unsigned short* __restrict__ xt){
  __shared__ float tile[64][65];
  const int b = blockIdx.z, c0 = blockIdx.y * 64, n0 = blockIdx.x * 64;
  const float* xb = x + (size_t)b * DIM * NTOK;
  const int t = threadIdx.x;
  #pragma unroll
  for (int p = 0; p < 4; p++){
    int idx = t + p * 256;
    int row = idx >> 4;
    int col = (idx & 15) << 2;
    float4 v = *(const float4*)(xb + (size_t)(c0 + row) * NTOK + n0 + col);
    tile[row][col] = v.x; tile[row][col+1] = v.y; tile[row][col+2] = v.z; tile[row][col+3] = v.w;
  }
  __syncthreads();
  unsigned short* xtb = xt + (size_t)b * NTOK * DIM;
  #pragma unroll
  for (int p = 0; p < 4; p++){
    int idx = t + p * 256;
    int nl = idx >> 4;
    int cl = (idx & 15) << 2;
    ushort4 o;
    o.x = f2bf(tile[cl+0][nl]); o.y = f2bf(tile[cl+1][nl]);
    o.z = f2bf(tile[cl+2][nl]); o.w = f2bf(tile[cl+3][nl]);
    *(ushort4*)(xtb + (size_t)(n0 + nl) * DIM + c0 + cl) = o;
  }
}

// ---------------- P2: convert Wqkv to bf16, PERMUTED row layout ----------------
// dest rows: [0..255]=q. Then 4 tiles of 128: tile p = [k heads 2p,2p+1 | v heads 2p,2p+1]
__global__ __launch_bounds__(256) void k_convert_w(const float* __restrict__ wqkv,
                                                   unsigned short* __restrict__ wq_bf){
  int i = blockIdx.x * 256 + threadIdx.x;  // 49152 threads: 768 rows x 64 groups of 4c
  int row = i >> 6;
  int c4 = (i & 63) * 4;
  int dst;
  if (row < 256)      dst = row;
  else if (row < 512){ int p = (row - 256) >> 6; int s = (row - 256) & 63; dst = 256 + p*128 + s; }
  else               { int p = (row - 512) >> 6; int s = (row - 512) & 63; dst = 256 + p*128 + 64 + s; }
  float4 v = *(const float4*)(wqkv + (size_t)row * DIM + c4);
  ushort4 o = { f2bf(v.x), f2bf(v.y), f2bf(v.z), f2bf(v.w) };
  *(ushort4*)(wq_bf + (size_t)dst * DIM + c4) = o;
}

// ---------------- K1: persistent qkv GEMM — 4-buffer depth-3 pipeline, 1 barrier/step ----------------
// 1536 blocks = 6 o-tiles x 256 chunks (b, nt2); block does pairs nt = nt2*2 + {0,1}, 8 K-steps.
// A (W-tile 128x256) in 64 VGPRs, staged once with a SINGLE vmcnt(0) drain through the 64KB staging
// region. B double... quad-buffered: 4 x 16KB, prefetch issued 3 steps ahead, counted vmcnt(4) in
// steady state (never 0 until tail). One s_barrier per step (buffer written at step s was last read
// at s-1, which the top-of-step barrier already fences). No mid-loop global stores: pair0's qn tile
// parks in regs until after the loop, so loop vmcnt counts are exact.
__global__ __launch_bounds__(512, 1) void k_qkv9(const unsigned short* __restrict__ wbf,
                                                 const unsigned short* __restrict__ xt,
                                                 unsigned short* __restrict__ qn,
                                                 float* __restrict__ kvp){
  __shared__ __align__(16) unsigned short sh[50176];  // 64KB staging (4 x 8192 u16) + 34KB bounce
  unsigned short* bsh = sh + 32768;                    // bounce: 128 x 136 u16
  const int t = threadIdx.x;
  const int w = t >> 6, l = t & 63;
  const int t16 = l & 15, quad = l >> 4;
  const int wm = w >> 1, wn = w & 1;     // wm 0..3 (o-quarter), wn 0..1 (n-half)
  // swizzle: 6 o-tiles sharing one chunk land on one XCD (48-bid window, bid%8 const per chunk)
  const int bid = blockIdx.x;
  const int super = bid / 48;            // 0..31
  const int rem = bid - super * 48;
  const int m = rem >> 3, lx = rem & 7;
  const int chunk = super * 8 + lx;      // 0..255
  const int b = chunk >> 4, nt2 = chunk & 15;
  const int o0 = m * 128;
  const bool isQ = (o0 < 256);
  const unsigned short* Bb = xt + ((size_t)b * NTOK + (size_t)nt2 * 256) * DIM;

  // ---- prologue: A-tile (128o x 256k) -> registers, ONE drain through the 4 staging buffers ----
  short8 a_reg[4][2][2];   // [k-chunk][i over o][kk] = 64 VGPRs
  {
    // wave w stages o-frag f=w (rows o0+w*16..+15), 8 slabs (c 0..3, kk 0..1), slab=1KB
    const unsigned short* srcA = wbf + (size_t)(o0 + w*16 + t16) * DIM + quad*8;
    #pragma unroll
    for (int c = 0; c < 4; c++){
      gload_lds16(srcA + c*64,      sh + ((w*4 + c)*2 + 0)*512);
      gload_lds16(srcA + c*64 + 32, sh + ((w*4 + c)*2 + 1)*512);
    }
    asm volatile("s_waitcnt vmcnt(0)" ::: "memory");
    __builtin_amdgcn_s_barrier();
    #pragma unroll
    for (int c = 0; c < 4; c++)
      #pragma unroll
      for (int i = 0; i < 2; i++)
        #pragma unroll
        for (int kk = 0; kk < 2; kk++)
          a_reg[c][i][kk] = *(const short8*)(sh + (((wm*2 + i)*4 + c)*2 + kk)*512 + l*8);
    asm volatile("s_waitcnt lgkmcnt(0)" ::: "memory");   // reads retired before B overwrites
    __builtin_amdgcn_s_barrier();
  }

  // B staging: step ss -> buffer ss%4; wave w stages its n-group (2 slabs)
#define STAGE(ss) { \
    const unsigned short* srcB = Bb + (size_t)((((ss) >> 2)*128) + w*16 + t16) * DIM + ((ss) & 3)*64 + quad*8; \
    unsigned short* db = sh + ((ss) & 3) * 8192; \
    gload_lds16(srcB,      db + (w*2 + 0)*512); \
    gload_lds16(srcB + 32, db + (w*2 + 1)*512); }

  STAGE(0); STAGE(1); STAGE(2);   // depth-3 prefetch primed

  f32x4 acc[2][4];
  #pragma unroll
  for (int i = 0; i < 2; i++)
    #pragma unroll
    for (int j = 0; j < 4; j++){ acc[i][j][0]=0.f; acc[i][j][1]=0.f; acc[i][j][2]=0.f; acc[i][j][3]=0.f; }
  f32x4 kvacc;
  kvacc[0]=0.f; kvacc[1]=0.f; kvacc[2]=0.f; kvacc[3]=0.f;
  uint4 qsave[4];   // pair0 qn tile parked here (q-path blocks only)

  // ---- main pipeline: 8 steps = 2 pairs x 4 K-steps ----
  #pragma unroll
  for (int s = 0; s < 8; s++){
    // outstanding at entry: B(s), B(s+1), B(s+2) (clamped to 7). Wait for B(s) only.
    if (s < 6)       { asm volatile("s_waitcnt vmcnt(4)" ::: "memory"); }
    else if (s == 6) { asm volatile("s_waitcnt vmcnt(2)" ::: "memory"); }
    else             { asm volatile("s_waitcnt vmcnt(0)" ::: "memory"); }
    __builtin_amdgcn_s_barrier();        // the ONLY per-step barrier
    const unsigned short* bufc = sh + (s & 3) * 8192;
    #pragma unroll
    for (int kk = 0; kk < 2; kk++){
      short8 bb[4];
      #pragma unroll
      for (int j = 0; j < 4; j++) bb[j] = *(const short8*)(bufc + ((wn*4 + j)*2 + kk)*512 + l*8);
      #pragma unroll
      for (int i = 0; i < 2; i++)
        #pragma unroll
        for (int j = 0; j < 4; j++)
          acc[i][j] = __builtin_amdgcn_mfma_f32_16x16x32_bf16(a_reg[s&3][i][kk], bb[j], acc[i][j], 0, 0, 0);
    }
    if (s < 5) STAGE(s + 3);             // write buf (s+3)%4 == (s-1)%4: last read at s-1, fenced above

    if ((s & 3) == 3){
      // ---- per-pair epilogue (prefetches for next pair stay in flight) ----
      if (isQ || wm < 2){
        #pragma unroll
        for (int i = 0; i < 2; i++)
          #pragma unroll
          for (int j = 0; j < 4; j++)
            #pragma unroll
            for (int r = 0; r < 4; r++) acc[i][j][r] = elu1(acc[i][j][r]);
        float sc[4];
        #pragma unroll
        for (int j = 0; j < 4; j++){
          float v = 0.f;
          #pragma unroll
          for (int i = 0; i < 2; i++)
            #pragma unroll
            for (int r = 0; r < 4; r++) v += acc[i][j][r];
          v += __shfl_xor(v, 16);
          v += __shfl_xor(v, 32);
          sc[j] = 1.0f / v;
        }
        #pragma unroll
        for (int i = 0; i < 2; i++)
          #pragma unroll
          for (int j = 0; j < 4; j++){
            float inv = sc[j];
            #pragma unroll
            for (int r = 0; r < 4; r++) acc[i][j][r] *= inv;
          }
      }
      if (isQ){
        // bounce [n_l][o_l] stride 136, packed b64
        #pragma unroll
        for (int i = 0; i < 2; i++)
          #pragma unroll
          for (int j = 0; j < 4; j++){
            int n_l = wn*64 + j*16 + t16;
            int o_l0 = wm*32 + i*16 + quad*4;
            ushort4 pk = { f2bf(acc[i][j][0]), f2bf(acc[i][j][1]),
                           f2bf(acc[i][j][2]), f2bf(acc[i][j][3]) };
            *(ushort4*)(bsh + n_l*136 + o_l0) = pk;
          }
        asm volatile("s_waitcnt lgkmcnt(0)" ::: "memory");
        __builtin_amdgcn_s_barrier();
        if (s == 3){
          // park pair0 in regs; ensure LDS reads retire before pair1 reuses bounce
          #pragma unroll
          for (int p2 = 0; p2 < 4; p2++){
            int gg = t + p2 * 512;
            int n_l = gg >> 4, c = gg & 15;
            qsave[p2] = *(const uint4*)(bsh + n_l*136 + c*8);
          }
          asm volatile("s_waitcnt lgkmcnt(0)" ::: "memory");
        } else {
          const int n0 = (nt2*2 + 1) * 128;
          unsigned short* dst = qn + (size_t)b * NTOK * DIM;
          #pragma unroll
          for (int p2 = 0; p2 < 4; p2++){
            int gg = t + p2 * 512;
            int n_l = gg >> 4, c = gg & 15;
            uint4 v = *(const uint4*)(bsh + n_l*136 + c*8);
            *(uint4*)(dst + (size_t)(n0 + n_l) * DIM + o0 + c*8) = v;
          }
        }
      } else {
        // bounce [o_l][n_l] stride 136 (K-contiguous along n for the kv MFMA)
        #pragma unroll
        for (int i = 0; i < 2; i++)
          #pragma unroll
          for (int j = 0; j < 4; j++){
            int n_l = wn*64 + j*16 + t16;
            #pragma unroll
            for (int r = 0; r < 4; r++){
              int o_l = wm*32 + i*16 + quad*4 + r;
              bsh[o_l*136 + n_l] = f2bf(acc[i][j][r]);
            }
          }
        asm volatile("s_waitcnt lgkmcnt(0)" ::: "memory");
        __builtin_amdgcn_s_barrier();
        // kv partial over this pair's 128 tokens, accumulated in registers across pairs
        const int hl = w >> 2, dh = (w >> 1) & 1, eh = w & 1;
        const unsigned short* kbase = bsh + (hl*32 + dh*16) * 136;        // normalized k rows
        const unsigned short* vbase = bsh + (64 + hl*32 + eh*16) * 136;   // raw v rows
        #pragma unroll
        for (int kk2 = 0; kk2 < 4; kk2++){
          int nn = kk2*32 + quad*8;
          short8 afrag = *(const short8*)(kbase + t16*136 + nn);
          short8 bfrag = *(const short8*)(vbase + t16*136 + nn);
          kvacc = __builtin_amdgcn_mfma_f32_16x16x32_bf16(afrag, bfrag, kvacc, 0, 0, 0);
        }
      }
      if (s == 3){
        #pragma unroll
        for (int i = 0; i < 2; i++)
          #pragma unroll
          for (int j = 0; j < 4; j++){ acc[i][j][0]=0.f; acc[i][j][1]=0.f; acc[i][j][2]=0.f; acc[i][j][3]=0.f; }
      }
    }
  }
#undef STAGE

  if (isQ){
    // deferred pair0 store
    const int n0 = (nt2*2) * 128;
    unsigned short* dst = qn + (size_t)b * NTOK * DIM;
    #pragma unroll
    for (int p2 = 0; p2 < 4; p2++){
      int gg = t + p2 * 512;
      int n_l = gg >> 4, c = gg & 15;
      *(uint4*)(dst + (size_t)(n0 + n_l) * DIM + o0 + c*8) = qsave[p2];
    }
  } else {
    const int pp = (o0 >> 7) - 2;          // head pair 0..3
    const int hl = w >> 2, dh = (w >> 1) & 1, eh = w & 1;
    float* dst = kvp + ((size_t)((b*8 + pp*2 + hl) * 16 + nt2)) * 1024;
    #pragma unroll
    for (int r = 0; r < 4; r++)
      dst[(dh*16 + quad*4 + r)*32 + eh*16 + t16] = kvacc[r];
  }
}

// ---------------- K3: reduce kv partials + fold Wproj: M[b][o][h*32+d] = sum_e Wp[o][h*32+e]*kv[d][e]
__global__ __launch_bounds__(256) void k_M(const float* __restrict__ kvp,
                                           const float* __restrict__ wproj,
                                           unsigned short* __restrict__ M){
  __shared__ float kvL[1024];
  __shared__ float wpL[8192];   // [o][e] 256x32
  const int t = threadIdx.x;
  const int h = blockIdx.x, b = blockIdx.y;
  const float* pbase = kvp + (size_t)((b*8 + h) * 16) * 1024;
  {
    float4 a = {0.f,0.f,0.f,0.f};
    #pragma unroll
    for (int p = 0; p < 16; p++){
      float4 v = *(const float4*)(pbase + (size_t)p*1024 + t*4);
      a.x += v.x; a.y += v.y; a.z += v.z; a.w += v.w;
    }
    *(float4*)(kvL + t*4) = a;
  }
  #pragma unroll
  for (int p = 0; p < 8; p++){
    int idx = t + p * 256;          // float4 index over 256x32
    int o = idx >> 3, e4 = idx & 7;
    *(float4*)(wpL + o*32 + e4*4) = *(const float4*)(wproj + (size_t)o * DIM + h*32 + e4*4);
  }
  __syncthreads();
  float wr[32];
  #pragma unroll
  for (int e = 0; e < 32; e++) wr[e] = wpL[t*32 + e];
  unsigned short md[32];
  #pragma unroll
  for (int d = 0; d < 32; d++){
    float a = 0.f;
    #pragma unroll
    for (int e = 0; e < 32; e++) a += wr[e] * kvL[d*32 + e];
    md[d] = f2bf(a);
  }
  unsigned short* dst = M + (size_t)b * 65536 + (size_t)t * DIM + h*32;
  #pragma unroll
  for (int q = 0; q < 4; q++) *(uint4*)(dst + q*8) = *(const uint4*)(md + q*8);
}

// ---------------- K4: out GEMM, FLIPPED operands (A=qn n-rows, B=M o-rows) ----------------
// D[row=quad*4+r -> n][col=t16 -> o]: per-lane 4 consecutive n => float4 epilogue, no bounce.
__global__ __launch_bounds__(512, 4) void k_out5(const unsigned short* __restrict__ M,
                                                 const unsigned short* __restrict__ qn,
                                                 const float* __restrict__ x,
                                                 const float* __restrict__ bproj,
                                                 float* __restrict__ out){
  __shared__ __align__(16) unsigned short As[8192];  // qn slabs (n rows)
  __shared__ __align__(16) unsigned short Bs[8192];  // M  slabs (o rows)
  const int t = threadIdx.x;
  const int w = t >> 6, l = t & 63;
  const int t16 = l & 15, quad = l >> 4;
  const int wm = w >> 1, wn = w & 1;     // wm 0..3 (n-quarter), wn 0..1 (o-half)
  // swizzle: 2 o-tiles sharing one (nt,b) within a 16-bid window
  const int bid = blockIdx.x;
  const int super = bid >> 4;
  const int rem = bid & 15;
  const int m = rem >> 3, lx = rem & 7;
  const int g = super * 8 + lx;          // 0..511
  const int nt = g >> 4, b = g & 15;
  const int o0 = m * 128, n0 = nt * 128;
  const unsigned short* A = qn + (size_t)b * NTOK * DIM;  // [n][256]
  const unsigned short* Bm = M + (size_t)b * 65536;       // [256][256]

  f32x4 acc[2][4];   // i over n (2x16), j over o (4x16)
  #pragma unroll
  for (int i = 0; i < 2; i++)
    #pragma unroll
    for (int j = 0; j < 4; j++){ acc[i][j][0]=0.f; acc[i][j][1]=0.f; acc[i][j][2]=0.f; acc[i][j][3]=0.f; }

  for (int k0 = 0; k0 < 256; k0 += 64){
    __syncthreads();
    #pragma unroll
    for (int s4 = 0; s4 < 4; s4++){
      int s = w * 4 + s4;            // 0..31
      int sl = s & 15;
      int tile = sl >> 1, kk = sl & 1;
      const unsigned short* src = (s < 16)
          ? (A  + (size_t)(n0 + tile*16 + t16) * DIM + k0 + kk*32 + quad*8)
          : (Bm + (size_t)(o0 + tile*16 + t16) * DIM + k0 + kk*32 + quad*8);
      gload_lds16(src, (s < 16) ? (As + sl * 512) : (Bs + sl * 512));
    }
    __syncthreads();
    #pragma unroll
    for (int kk = 0; kk < 2; kk++){
      short8 a[2], bb[4];
      #pragma unroll
      for (int i = 0; i < 2; i++) a[i]  = *(const short8*)(As + ((wm*2 + i)*2 + kk) * 512 + l * 8);
      #pragma unroll
      for (int j = 0; j < 4; j++) bb[j] = *(const short8*)(Bs + ((wn*4 + j)*2 + kk) * 512 + l * 8);
      #pragma unroll
      for (int i = 0; i < 2; i++)
        #pragma unroll
        for (int j = 0; j < 4; j++)
          acc[i][j] = __builtin_amdgcn_mfma_f32_16x16x32_bf16(a[i], bb[j], acc[i][j], 0, 0, 0);
    }
  }

  // epilogue: out[o][n] = acc + bias[o] + x[o][n], per-lane float4 along n
  const float* xb = x + (size_t)b * DIM * NTOK;
  float* ob = out + (size_t)b * DIM * NTOK;
  #pragma unroll
  for (int j = 0; j < 4; j++){
    int o = o0 + wn*64 + j*16 + t16;
    float bias = bproj[o];
    #pragma unroll
    for (int i = 0; i < 2; i++){
      int n = n0 + wm*32 + i*16 + quad*4;
      float4 xv = *(const float4*)(xb + (size_t)o * NTOK + n);
      float4 res = { acc[i][j][0] + bias + xv.x,
                     acc[i][j][1] + bias + xv.y,
                     acc[i][j][2] + bias + xv.z,
                     acc[i][j][3] + bias + xv.w };
      *(float4*)(ob + (size_t)o * NTOK + n) = res;
    }
  }
}

extern "C" void kernel_launch(void* const* d_in, const int* in_sizes, int n_in,
                              void* d_out, int out_size, void* d_ws, size_t ws_size,
                              hipStream_t stream){
  const float* x     = (const float*)d_in[0];
  const float* wqkv  = (const float*)d_in[1];
  const float* wproj = (const float*)d_in[2];
  const float* bproj = (const float*)d_in[3];
  float* out = (float*)d_out;
  char* ws = (char*)d_ws;

  // ws layout:
  unsigned short* xt   = (unsigned short*)(ws);                        // 32 MiB [b][n][256]
  unsigned short* qn   = (unsigned short*)(ws + ((size_t)32 << 20));   // 32 MiB [b][n][256]
  float* kvp           = (float*)(ws + ((size_t)64 << 20));            // 8 MiB [b][h][nt2 16][1024]
  unsigned short* M    = (unsigned short*)(ws + ((size_t)80 << 20));   // 2 MiB [b][256][256]
  unsigned short* wqbf = (unsigned short*)(ws + ((size_t)82 << 20));   // 384 KiB permuted

  k_transpose_x<<<dim3(64, 4, 16), 256, 0, stream>>>(x, xt);
  k_convert_w  <<<dim3(192), 256, 0, stream>>>(wqkv, wqbf);
  k_qkv9       <<<dim3(1536), 512, 0, stream>>>(wqbf, xt, qn, kvp);
  k_M          <<<dim3(8, 16), 256, 0, stream>>>(kvp, wproj, M);
  k_out5       <<<dim3(1024), 512, 0, stream>>>(M, qn, x, bproj, out);
}

// Round 6
// 220.263 us; speedup vs baseline: 1.1093x; 1.1093x over previous
//
#include <hip/hip_runtime.h>
#include <stdint.h>
#include <stddef.h>

#define DIM   256
#define NH    8
#define HD    32
#define BATCH 16
#define NTOK  4096   // 64*64

typedef __attribute__((ext_vector_type(8))) short short8;
typedef __attribute__((ext_vector_type(4))) float f32x4;

__device__ __forceinline__ unsigned short f2bf(float x){
  unsigned u = __float_as_uint(x);
  u += 0x7fffu + ((u >> 16) & 1u);       // RNE
  return (unsigned short)(u >> 16);
}
__device__ __forceinline__ float elu1(float v){
  return (v > 0.f) ? (v + 1.f) : __expf(v);
}
// async global->LDS, 16B per lane. lds dest = wave-uniform base + lane*16.
__device__ __forceinline__ void gload_lds16(const void* g, void* lds){
  __builtin_amdgcn_global_load_lds(
      (const __attribute__((address_space(1))) unsigned int*)g,
      (__attribute__((address_space(3))) unsigned int*)lds, 16, 0, 0);
}

// ---------------- P1: x [b][c][n] f32 -> x_t [b][n][c] bf16 ----------------
__global__ __launch_bounds__(256) void k_transpose_x(const float* __restrict__ x,
                                                     unsigned short* __restrict__ xt){
  __shared__ float tile[64][65];
  const int b = blockIdx.z, c0 = blockIdx.y * 64, n0 = blockIdx.x * 64;
  const float* xb = x + (size_t)b * DIM * NTOK;
  const int t = threadIdx.x;
  #pragma unroll
  for (int p = 0; p < 4; p++){
    int idx = t + p * 256;
    int row = idx >> 4;
    int col = (idx & 15) << 2;
    float4 v = *(const float4*)(xb + (size_t)(c0 + row) * NTOK + n0 + col);
    tile[row][col] = v.x; tile[row][col+1] = v.y; tile[row][col+2] = v.z; tile[row][col+3] = v.w;
  }
  __syncthreads();
  unsigned short* xtb = xt + (size_t)b * NTOK * DIM;
  #pragma unroll
  for (int p = 0; p < 4; p++){
    int idx = t + p * 256;
    int nl = idx >> 4;
    int cl = (idx & 15) << 2;
    ushort4 o;
    o.x = f2bf(tile[cl+0][nl]); o.y = f2bf(tile[cl+1][nl]);
    o.z = f2bf(tile[cl+2][nl]); o.w = f2bf(tile[cl+3][nl]);
    *(ushort4*)(xtb + (size_t)(n0 + nl) * DIM + c0 + cl) = o;
  }
}

// ---------------- P2: convert Wqkv to bf16, PERMUTED row layout ----------------
// dest rows: [0..255]=q. Then 4 tiles of 128: tile p = [k heads 2p,2p+1 | v heads 2p,2p+1]
__global__ __launch_bounds__(256) void k_convert_w(const float* __restrict__ wqkv,
                                                   unsigned short* __restrict__ wq_bf){
  int i = blockIdx.x * 256 + threadIdx.x;  // 49152 threads: 768 rows x 64 groups of 4c
  int row = i >> 6;
  int c4 = (i & 63) * 4;
  int dst;
  if (row < 256)      dst = row;
  else if (row < 512){ int p = (row - 256) >> 6; int s = (row - 256) & 63; dst = 256 + p*128 + s; }
  else               { int p = (row - 512) >> 6; int s = (row - 512) & 63; dst = 256 + p*128 + 64 + s; }
  float4 v = *(const float4*)(wqkv + (size_t)row * DIM + c4);
  ushort4 o = { f2bf(v.x), f2bf(v.y), f2bf(v.z), f2bf(v.w) };
  *(ushort4*)(wq_bf + (size_t)dst * DIM + c4) = o;
}

// ---------------- K1: persistent qkv GEMM — W in regs, 2-buffer counted-vmcnt pipeline ----------------
// = k_qkv8 (R4, best) + two fixes, occupancy-neutral (LDS 67584 -> 2 blocks/CU, VGPR ~84):
//  (1) single-drain A-prologue: all 64KB of A staged in ONE round through staging+bounce regions
//      (A slabs dead after a_reg reads; B/bounce reuse the space) -> one vmcnt(0) round-trip not two.
//  (2) corrected counted waits around the s=3 q-store: queue at s=4 is [S4,S5,stores]; with in-order
//      retirement (m135) q-path uses vmcnt(6)@s4, vmcnt(6)@s5, vmcnt(2)@s6, vmcnt(0)@s7 so only the
//      needed stage is drained (k_qkv8's vmcnt(2)@s4 force-drained S5 + stores). kv-path: 2,...,2,0.
__global__ __launch_bounds__(512, 1) void k_qkv10(const unsigned short* __restrict__ wbf,
                                                  const unsigned short* __restrict__ xt,
                                                  unsigned short* __restrict__ qn,
                                                  float* __restrict__ kvp){
  __shared__ __align__(16) unsigned short sh[33792];  // 32KB staging (2x 8192 u16) + 34KB bounce
  unsigned short* bsh = sh + 16384;                    // bounce: 128 x 136 u16
  const int t = threadIdx.x;
  const int w = t >> 6, l = t & 63;
  const int t16 = l & 15, quad = l >> 4;
  const int wm = w >> 1, wn = w & 1;     // wm 0..3 (o-quarter), wn 0..1 (n-half)
  // swizzle: 6 o-tiles sharing one chunk land on one XCD (48-bid window, bid%8 const per chunk)
  const int bid = blockIdx.x;
  const int super = bid / 48;            // 0..31
  const int rem = bid - super * 48;
  const int m = rem >> 3, lx = rem & 7;
  const int chunk = super * 8 + lx;      // 0..255
  const int b = chunk >> 4, nt2 = chunk & 15;
  const int o0 = m * 128;
  const bool isQ = (o0 < 256);
  const unsigned short* Bb = xt + ((size_t)b * NTOK + (size_t)nt2 * 256) * DIM;
  const int rowL = (w*16 + t16) * DIM + quad*8;   // per-lane staging offset

  // ---- prologue: A-tile (128o x 256k) -> registers, ONE drain through 64 slabs (staging+bounce) ----
  short8 a_reg[4][2][2];   // [k-chunk c][i over o][kk] = 64 VGPRs
  {
    const unsigned short* srcA = wbf + (size_t)(o0 + w*16 + t16) * DIM + quad*8;
    #pragma unroll
    for (int c = 0; c < 4; c++){
      gload_lds16(srcA + c*64,      sh + (w*8 + c*2 + 0)*512);
      gload_lds16(srcA + c*64 + 32, sh + (w*8 + c*2 + 1)*512);
    }
    asm volatile("s_waitcnt vmcnt(0)" ::: "memory");
    __builtin_amdgcn_s_barrier();
    #pragma unroll
    for (int c = 0; c < 4; c++)
      #pragma unroll
      for (int i = 0; i < 2; i++)
        #pragma unroll
        for (int kk = 0; kk < 2; kk++)
          a_reg[c][i][kk] = *(const short8*)(sh + ((wm*2 + i)*8 + c*2 + kk)*512 + l*8);
    asm volatile("s_waitcnt lgkmcnt(0)" ::: "memory");   // reads retired before B overwrites slabs
    __builtin_amdgcn_s_barrier();
  }

  // B staging: step ss -> buffer ss&1; wave w stages its n-group (2 slabs, kk 0/1)
#define STAGE(ss) { \
    const unsigned short* srcB = Bb + (size_t)(((ss) >> 2)*128) * DIM + rowL + ((ss) & 3)*64; \
    unsigned short* db = sh + ((ss) & 1) * 8192; \
    gload_lds16(srcB,      db + (w*2 + 0)*512); \
    gload_lds16(srcB + 32, db + (w*2 + 1)*512); }

  STAGE(0); STAGE(1);   // depth-2 primed

  f32x4 acc[2][4];
  #pragma unroll
  for (int i = 0; i < 2; i++)
    #pragma unroll
    for (int j = 0; j < 4; j++){ acc[i][j][0]=0.f; acc[i][j][1]=0.f; acc[i][j][2]=0.f; acc[i][j][3]=0.f; }
  f32x4 kvacc;
  kvacc[0]=0.f; kvacc[1]=0.f; kvacc[2]=0.f; kvacc[3]=0.f;

  // ---- main pipeline: 8 steps = 2 pairs x 4 K-steps, depth-2 prefetch ----
  #pragma unroll
  for (int s = 0; s < 8; s++){
    // counted waits (in-order retirement): retire exactly the stage needed this step.
    if (s < 4)       { asm volatile("s_waitcnt vmcnt(2)" ::: "memory"); }
    else if (s < 6)  { if (isQ) { asm volatile("s_waitcnt vmcnt(6)" ::: "memory"); }
                       else     { asm volatile("s_waitcnt vmcnt(2)" ::: "memory"); } }
    else if (s == 6) { asm volatile("s_waitcnt vmcnt(2)" ::: "memory"); }
    else             { asm volatile("s_waitcnt vmcnt(0)" ::: "memory"); }
    __builtin_amdgcn_s_barrier();                         // all waves' STAGE(s) complete
    const unsigned short* bufc = sh + (s & 1) * 8192;
    #pragma unroll
    for (int kk = 0; kk < 2; kk++){
      short8 bb[4];
      #pragma unroll
      for (int j = 0; j < 4; j++) bb[j] = *(const short8*)(bufc + ((wn*4 + j)*2 + kk)*512 + l*8);
      #pragma unroll
      for (int i = 0; i < 2; i++)
        #pragma unroll
        for (int j = 0; j < 4; j++)
          acc[i][j] = __builtin_amdgcn_mfma_f32_16x16x32_bf16(a_reg[s&3][i][kk], bb[j], acc[i][j], 0, 0, 0);
    }
    __builtin_amdgcn_s_barrier();       // all waves consumed buf[s&1] (MFMA forces lgkm wait)
    if (s < 6) STAGE(s + 2);            // refill the buffer just consumed

    if ((s & 3) == 3){
      // ---- per-pair epilogue (next pair's prefetches stay in flight) ----
      const int n0 = (nt2*2 + (s >> 2)) * 128;
      if (isQ || wm < 2){
        #pragma unroll
        for (int i = 0; i < 2; i++)
          #pragma unroll
          for (int j = 0; j < 4; j++)
            #pragma unroll
            for (int r = 0; r < 4; r++) acc[i][j][r] = elu1(acc[i][j][r]);
        float sc[4];
        #pragma unroll
        for (int j = 0; j < 4; j++){
          float v = 0.f;
          #pragma unroll
          for (int i = 0; i < 2; i++)
            #pragma unroll
            for (int r = 0; r < 4; r++) v += acc[i][j][r];
          v += __shfl_xor(v, 16);
          v += __shfl_xor(v, 32);
          sc[j] = 1.0f / v;
        }
        #pragma unroll
        for (int i = 0; i < 2; i++)
          #pragma unroll
          for (int j = 0; j < 4; j++){
            float inv = sc[j];
            #pragma unroll
            for (int r = 0; r < 4; r++) acc[i][j][r] *= inv;
          }
      }
      if (isQ){
        // bounce [n_l][o_l] stride 136, packed b64
        #pragma unroll
        for (int i = 0; i < 2; i++)
          #pragma unroll
          for (int j = 0; j < 4; j++){
            int n_l = wn*64 + j*16 + t16;
            int o_l0 = wm*32 + i*16 + quad*4;
            ushort4 pk = { f2bf(acc[i][j][0]), f2bf(acc[i][j][1]),
                           f2bf(acc[i][j][2]), f2bf(acc[i][j][3]) };
            *(ushort4*)(bsh + n_l*136 + o_l0) = pk;
          }
        asm volatile("s_waitcnt lgkmcnt(0)" ::: "memory");   // LDS writes visible (no vmcnt drain)
        __builtin_amdgcn_s_barrier();
        unsigned short* dst = qn + (size_t)b * NTOK * DIM;
        #pragma unroll
        for (int p2 = 0; p2 < 4; p2++){
          int gg = t + p2 * 512;
          int n_l = gg >> 4, c = gg & 15;
          uint4 v = *(const uint4*)(bsh + n_l*136 + c*8);
          *(uint4*)(dst + (size_t)(n0 + n_l) * DIM + o0 + c*8) = v;
        }
      } else {
        // bounce [o_l][n_l] stride 136 (K-contiguous along n for the kv MFMA)
        #pragma unroll
        for (int i = 0; i < 2; i++)
          #pragma unroll
          for (int j = 0; j < 4; j++){
            int n_l = wn*64 + j*16 + t16;
            #pragma unroll
            for (int r = 0; r < 4; r++){
              int o_l = wm*32 + i*16 + quad*4 + r;
              bsh[o_l*136 + n_l] = f2bf(acc[i][j][r]);
            }
          }
        asm volatile("s_waitcnt lgkmcnt(0)" ::: "memory");
        __builtin_amdgcn_s_barrier();
        // kv partial over this pair's 128 tokens, accumulated in registers across pairs
        const int hl = w >> 2, dh = (w >> 1) & 1, eh = w & 1;
        const unsigned short* kbase = bsh + (hl*32 + dh*16) * 136;        // normalized k rows
        const unsigned short* vbase = bsh + (64 + hl*32 + eh*16) * 136;   // raw v rows
        #pragma unroll
        for (int kk2 = 0; kk2 < 4; kk2++){
          int nn = kk2*32 + quad*8;
          short8 afrag = *(const short8*)(kbase + t16*136 + nn);
          short8 bfrag = *(const short8*)(vbase + t16*136 + nn);
          kvacc = __builtin_amdgcn_mfma_f32_16x16x32_bf16(afrag, bfrag, kvacc, 0, 0, 0);
        }
      }
      if (s == 3){
        #pragma unroll
        for (int i = 0; i < 2; i++)
          #pragma unroll
          for (int j = 0; j < 4; j++){ acc[i][j][0]=0.f; acc[i][j][1]=0.f; acc[i][j][2]=0.f; acc[i][j][3]=0.f; }
      }
    }
  }
#undef STAGE

  if (!isQ){
    const int pp = (o0 >> 7) - 2;          // head pair 0..3
    const int hl = w >> 2, dh = (w >> 1) & 1, eh = w & 1;
    float* dst = kvp + ((size_t)((b*8 + pp*2 + hl) * 16 + nt2)) * 1024;
    #pragma unroll
    for (int r = 0; r < 4; r++)
      dst[(dh*16 + quad*4 + r)*32 + eh*16 + t16] = kvacc[r];
  }
}

// ---------------- K3: reduce kv partials + fold Wproj: M[b][o][h*32+d] = sum_e Wp[o][h*32+e]*kv[d][e]
__global__ __launch_bounds__(256) void k_M(const float* __restrict__ kvp,
                                           const float* __restrict__ wproj,
                                           unsigned short* __restrict__ M){
  __shared__ float kvL[1024];
  __shared__ float wpL[8192];   // [o][e] 256x32
  const int t = threadIdx.x;
  const int h = blockIdx.x, b = blockIdx.y;
  const float* pbase = kvp + (size_t)((b*8 + h) * 16) * 1024;
  {
    float4 a = {0.f,0.f,0.f,0.f};
    #pragma unroll
    for (int p = 0; p < 16; p++){
      float4 v = *(const float4*)(pbase + (size_t)p*1024 + t*4);
      a.x += v.x; a.y += v.y; a.z += v.z; a.w += v.w;
    }
    *(float4*)(kvL + t*4) = a;
  }
  #pragma unroll
  for (int p = 0; p < 8; p++){
    int idx = t + p * 256;          // float4 index over 256x32
    int o = idx >> 3, e4 = idx & 7;
    *(float4*)(wpL + o*32 + e4*4) = *(const float4*)(wproj + (size_t)o * DIM + h*32 + e4*4);
  }
  __syncthreads();
  float wr[32];
  #pragma unroll
  for (int e = 0; e < 32; e++) wr[e] = wpL[t*32 + e];
  unsigned short md[32];
  #pragma unroll
  for (int d = 0; d < 32; d++){
    float a = 0.f;
    #pragma unroll
    for (int e = 0; e < 32; e++) a += wr[e] * kvL[d*32 + e];
    md[d] = f2bf(a);
  }
  unsigned short* dst = M + (size_t)b * 65536 + (size_t)t * DIM + h*32;
  #pragma unroll
  for (int q = 0; q < 4; q++) *(uint4*)(dst + q*8) = *(const uint4*)(md + q*8);
}

// ---------------- K4: out GEMM, FLIPPED operands (A=qn n-rows, B=M o-rows) ----------------
// D[row=quad*4+r -> n][col=t16 -> o]: per-lane 4 consecutive n => float4 epilogue, no bounce.
__global__ __launch_bounds__(512, 4) void k_out5(const unsigned short* __restrict__ M,
                                                 const unsigned short* __restrict__ qn,
                                                 const float* __restrict__ x,
                                                 const float* __restrict__ bproj,
                                                 float* __restrict__ out){
  __shared__ __align__(16) unsigned short As[8192];  // qn slabs (n rows)
  __shared__ __align__(16) unsigned short Bs[8192];  // M  slabs (o rows)
  const int t = threadIdx.x;
  const int w = t >> 6, l = t & 63;
  const int t16 = l & 15, quad = l >> 4;
  const int wm = w >> 1, wn = w & 1;     // wm 0..3 (n-quarter), wn 0..1 (o-half)
  // swizzle: 2 o-tiles sharing one (nt,b) within a 16-bid window
  const int bid = blockIdx.x;
  const int super = bid >> 4;
  const int rem = bid & 15;
  const int m = rem >> 3, lx = rem & 7;
  const int g = super * 8 + lx;          // 0..511
  const int nt = g >> 4, b = g & 15;
  const int o0 = m * 128, n0 = nt * 128;
  const unsigned short* A = qn + (size_t)b * NTOK * DIM;  // [n][256]
  const unsigned short* Bm = M + (size_t)b * 65536;       // [256][256]

  f32x4 acc[2][4];   // i over n (2x16), j over o (4x16)
  #pragma unroll
  for (int i = 0; i < 2; i++)
    #pragma unroll
    for (int j = 0; j < 4; j++){ acc[i][j][0]=0.f; acc[i][j][1]=0.f; acc[i][j][2]=0.f; acc[i][j][3]=0.f; }

  for (int k0 = 0; k0 < 256; k0 += 64){
    __syncthreads();
    #pragma unroll
    for (int s4 = 0; s4 < 4; s4++){
      int s = w * 4 + s4;            // 0..31
      int sl = s & 15;
      int tile = sl >> 1, kk = sl & 1;
      const unsigned short* src = (s < 16)
          ? (A  + (size_t)(n0 + tile*16 + t16) * DIM + k0 + kk*32 + quad*8)
          : (Bm + (size_t)(o0 + tile*16 + t16) * DIM + k0 + kk*32 + quad*8);
      gload_lds16(src, (s < 16) ? (As + sl * 512) : (Bs + sl * 512));
    }
    __syncthreads();
    #pragma unroll
    for (int kk = 0; kk < 2; kk++){
      short8 a[2], bb[4];
      #pragma unroll
      for (int i = 0; i < 2; i++) a[i]  = *(const short8*)(As + ((wm*2 + i)*2 + kk) * 512 + l * 8);
      #pragma unroll
      for (int j = 0; j < 4; j++) bb[j] = *(const short8*)(Bs + ((wn*4 + j)*2 + kk) * 512 + l * 8);
      #pragma unroll
      for (int i = 0; i < 2; i++)
        #pragma unroll
        for (int j = 0; j < 4; j++)
          acc[i][j] = __builtin_amdgcn_mfma_f32_16x16x32_bf16(a[i], bb[j], acc[i][j], 0, 0, 0);
    }
  }

  // epilogue: out[o][n] = acc + bias[o] + x[o][n], per-lane float4 along n
  const float* xb = x + (size_t)b * DIM * NTOK;
  float* ob = out + (size_t)b * DIM * NTOK;
  #pragma unroll
  for (int j = 0; j < 4; j++){
    int o = o0 + wn*64 + j*16 + t16;
    float bias = bproj[o];
    #pragma unroll
    for (int i = 0; i < 2; i++){
      int n = n0 + wm*32 + i*16 + quad*4;
      float4 xv = *(const float4*)(xb + (size_t)o * NTOK + n);
      float4 res = { acc[i][j][0] + bias + xv.x,
                     acc[i][j][1] + bias + xv.y,
                     acc[i][j][2] + bias + xv.z,
                     acc[i][j][3] + bias + xv.w };
      *(float4*)(ob + (size_t)o * NTOK + n) = res;
    }
  }
}

extern "C" void kernel_launch(void* const* d_in, const int* in_sizes, int n_in,
                              void* d_out, int out_size, void* d_ws, size_t ws_size,
                              hipStream_t stream){
  const float* x     = (const float*)d_in[0];
  const float* wqkv  = (const float*)d_in[1];
  const float* wproj = (const float*)d_in[2];
  const float* bproj = (const float*)d_in[3];
  float* out = (float*)d_out;
  char* ws = (char*)d_ws;

  // ws layout:
  unsigned short* xt   = (unsigned short*)(ws);                        // 32 MiB [b][n][256]
  unsigned short* qn   = (unsigned short*)(ws + ((size_t)32 << 20));   // 32 MiB [b][n][256]
  float* kvp           = (float*)(ws + ((size_t)64 << 20));            // 8 MiB [b][h][nt2 16][1024]
  unsigned short* M    = (unsigned short*)(ws + ((size_t)80 << 20));   // 2 MiB [b][256][256]
  unsigned short* wqbf = (unsigned short*)(ws + ((size_t)82 << 20));   // 384 KiB permuted

  k_transpose_x<<<dim3(64, 4, 16), 256, 0, stream>>>(x, xt);
  k_convert_w  <<<dim3(192), 256, 0, stream>>>(wqkv, wqbf);
  k_qkv10      <<<dim3(1536), 512, 0, stream>>>(wqbf, xt, qn, kvp);
  k_M          <<<dim3(8, 16), 256, 0, stream>>>(kvp, wproj, M);
  k_out5       <<<dim3(1024), 512, 0, stream>>>(M, qn, x, bproj, out);
}

// Round 7
// 219.926 us; speedup vs baseline: 1.1110x; 1.0015x over previous
//
#include <hip/hip_runtime.h>
#include <stdint.h>
#include <stddef.h>

#define DIM   256
#define NH    8
#define HD    32
#define BATCH 16
#define NTOK  4096   // 64*64

typedef __attribute__((ext_vector_type(8))) short short8;
typedef __attribute__((ext_vector_type(4))) float f32x4;

__device__ __forceinline__ unsigned short f2bf(float x){
  unsigned u = __float_as_uint(x);
  u += 0x7fffu + ((u >> 16) & 1u);       // RNE
  return (unsigned short)(u >> 16);
}
__device__ __forceinline__ float elu1(float v){
  return (v > 0.f) ? (v + 1.f) : __expf(v);
}
// async global->LDS, 16B per lane. lds dest = wave-uniform base + lane*16.
__device__ __forceinline__ void gload_lds16(const void* g, void* lds){
  __builtin_amdgcn_global_load_lds(
      (const __attribute__((address_space(1))) unsigned int*)g,
      (__attribute__((address_space(3))) unsigned int*)lds, 16, 0, 0);
}

// ---------------- P1+P2 merged: transpose x AND convert Wqkv in one launch ----------------
// z = 0..15: transpose batch z (x [c][n] f32 -> xt [n][c] bf16)
// z = 16   : convert Wqkv -> bf16 permuted (first 192 of the 256 (x,y) blocks)
__global__ __launch_bounds__(256) void k_prep(const float* __restrict__ x,
                                              unsigned short* __restrict__ xt,
                                              const float* __restrict__ wqkv,
                                              unsigned short* __restrict__ wq_bf){
  const int t = threadIdx.x;
  if (blockIdx.z < 16){
    __shared__ float tile[64][65];
    const int b = blockIdx.z, c0 = blockIdx.y * 64, n0 = blockIdx.x * 64;
    const float* xb = x + (size_t)b * DIM * NTOK;
    #pragma unroll
    for (int p = 0; p < 4; p++){
      int idx = t + p * 256;
      int row = idx >> 4;
      int col = (idx & 15) << 2;
      float4 v = *(const float4*)(xb + (size_t)(c0 + row) * NTOK + n0 + col);
      tile[row][col] = v.x; tile[row][col+1] = v.y; tile[row][col+2] = v.z; tile[row][col+3] = v.w;
    }
    __syncthreads();
    unsigned short* xtb = xt + (size_t)b * NTOK * DIM;
    #pragma unroll
    for (int p = 0; p < 4; p++){
      int idx = t + p * 256;
      int nl = idx >> 4;
      int cl = (idx & 15) << 2;
      ushort4 o;
      o.x = f2bf(tile[cl+0][nl]); o.y = f2bf(tile[cl+1][nl]);
      o.z = f2bf(tile[cl+2][nl]); o.w = f2bf(tile[cl+3][nl]);
      *(ushort4*)(xtb + (size_t)(n0 + nl) * DIM + c0 + cl) = o;
    }
  } else {
    const int blk = blockIdx.y * 64 + blockIdx.x;   // 0..255, use first 192
    if (blk >= 192) return;
    int i = blk * 256 + t;            // 49152 threads: 768 rows x 64 groups of 4c
    int row = i >> 6;
    int c4 = (i & 63) * 4;
    int dst;
    if (row < 256)      dst = row;
    else if (row < 512){ int p = (row - 256) >> 6; int s = (row - 256) & 63; dst = 256 + p*128 + s; }
    else               { int p = (row - 512) >> 6; int s = (row - 512) & 63; dst = 256 + p*128 + 64 + s; }
    float4 v = *(const float4*)(wqkv + (size_t)row * DIM + c4);
    ushort4 o = { f2bf(v.x), f2bf(v.y), f2bf(v.z), f2bf(v.w) };
    *(ushort4*)(wq_bf + (size_t)dst * DIM + c4) = o;
  }
}

// ---------------- K1: persistent qkv GEMM — k_qkv10 + T5 setprio around MFMA cluster ----------------
__global__ __launch_bounds__(512, 1) void k_qkv11(const unsigned short* __restrict__ wbf,
                                                  const unsigned short* __restrict__ xt,
                                                  unsigned short* __restrict__ qn,
                                                  float* __restrict__ kvp){
  __shared__ __align__(16) unsigned short sh[33792];  // 32KB staging (2x 8192 u16) + 34KB bounce
  unsigned short* bsh = sh + 16384;                    // bounce: 128 x 136 u16
  const int t = threadIdx.x;
  const int w = t >> 6, l = t & 63;
  const int t16 = l & 15, quad = l >> 4;
  const int wm = w >> 1, wn = w & 1;     // wm 0..3 (o-quarter), wn 0..1 (n-half)
  const int bid = blockIdx.x;
  const int super = bid / 48;            // 0..31
  const int rem = bid - super * 48;
  const int m = rem >> 3, lx = rem & 7;
  const int chunk = super * 8 + lx;      // 0..255
  const int b = chunk >> 4, nt2 = chunk & 15;
  const int o0 = m * 128;
  const bool isQ = (o0 < 256);
  const unsigned short* Bb = xt + ((size_t)b * NTOK + (size_t)nt2 * 256) * DIM;
  const int rowL = (w*16 + t16) * DIM + quad*8;   // per-lane staging offset

  // ---- prologue: A-tile (128o x 256k) -> registers, ONE drain through 64 slabs ----
  short8 a_reg[4][2][2];   // [k-chunk c][i over o][kk] = 64 VGPRs
  {
    const unsigned short* srcA = wbf + (size_t)(o0 + w*16 + t16) * DIM + quad*8;
    #pragma unroll
    for (int c = 0; c < 4; c++){
      gload_lds16(srcA + c*64,      sh + (w*8 + c*2 + 0)*512);
      gload_lds16(srcA + c*64 + 32, sh + (w*8 + c*2 + 1)*512);
    }
    asm volatile("s_waitcnt vmcnt(0)" ::: "memory");
    __builtin_amdgcn_s_barrier();
    #pragma unroll
    for (int c = 0; c < 4; c++)
      #pragma unroll
      for (int i = 0; i < 2; i++)
        #pragma unroll
        for (int kk = 0; kk < 2; kk++)
          a_reg[c][i][kk] = *(const short8*)(sh + ((wm*2 + i)*8 + c*2 + kk)*512 + l*8);
    asm volatile("s_waitcnt lgkmcnt(0)" ::: "memory");
    __builtin_amdgcn_s_barrier();
  }

#define STAGE(ss) { \
    const unsigned short* srcB = Bb + (size_t)(((ss) >> 2)*128) * DIM + rowL + ((ss) & 3)*64; \
    unsigned short* db = sh + ((ss) & 1) * 8192; \
    gload_lds16(srcB,      db + (w*2 + 0)*512); \
    gload_lds16(srcB + 32, db + (w*2 + 1)*512); }

  STAGE(0); STAGE(1);   // depth-2 primed

  f32x4 acc[2][4];
  #pragma unroll
  for (int i = 0; i < 2; i++)
    #pragma unroll
    for (int j = 0; j < 4; j++){ acc[i][j][0]=0.f; acc[i][j][1]=0.f; acc[i][j][2]=0.f; acc[i][j][3]=0.f; }
  f32x4 kvacc;
  kvacc[0]=0.f; kvacc[1]=0.f; kvacc[2]=0.f; kvacc[3]=0.f;

  #pragma unroll
  for (int s = 0; s < 8; s++){
    if (s < 4)       { asm volatile("s_waitcnt vmcnt(2)" ::: "memory"); }
    else if (s < 6)  { if (isQ) { asm volatile("s_waitcnt vmcnt(6)" ::: "memory"); }
                       else     { asm volatile("s_waitcnt vmcnt(2)" ::: "memory"); } }
    else if (s == 6) { asm volatile("s_waitcnt vmcnt(2)" ::: "memory"); }
    else             { asm volatile("s_waitcnt vmcnt(0)" ::: "memory"); }
    __builtin_amdgcn_s_barrier();
    const unsigned short* bufc = sh + (s & 1) * 8192;
    __builtin_amdgcn_s_setprio(1);
    #pragma unroll
    for (int kk = 0; kk < 2; kk++){
      short8 bb[4];
      #pragma unroll
      for (int j = 0; j < 4; j++) bb[j] = *(const short8*)(bufc + ((wn*4 + j)*2 + kk)*512 + l*8);
      #pragma unroll
      for (int i = 0; i < 2; i++)
        #pragma unroll
        for (int j = 0; j < 4; j++)
          acc[i][j] = __builtin_amdgcn_mfma_f32_16x16x32_bf16(a_reg[s&3][i][kk], bb[j], acc[i][j], 0, 0, 0);
    }
    __builtin_amdgcn_s_setprio(0);
    __builtin_amdgcn_s_barrier();
    if (s < 6) STAGE(s + 2);

    if ((s & 3) == 3){
      const int n0 = (nt2*2 + (s >> 2)) * 128;
      if (isQ || wm < 2){
        #pragma unroll
        for (int i = 0; i < 2; i++)
          #pragma unroll
          for (int j = 0; j < 4; j++)
            #pragma unroll
            for (int r = 0; r < 4; r++) acc[i][j][r] = elu1(acc[i][j][r]);
        float sc[4];
        #pragma unroll
        for (int j = 0; j < 4; j++){
          float v = 0.f;
          #pragma unroll
          for (int i = 0; i < 2; i++)
            #pragma unroll
            for (int r = 0; r < 4; r++) v += acc[i][j][r];
          v += __shfl_xor(v, 16);
          v += __shfl_xor(v, 32);
          sc[j] = 1.0f / v;
        }
        #pragma unroll
        for (int i = 0; i < 2; i++)
          #pragma unroll
          for (int j = 0; j < 4; j++){
            float inv = sc[j];
            #pragma unroll
            for (int r = 0; r < 4; r++) acc[i][j][r] *= inv;
          }
      }
      if (isQ){
        #pragma unroll
        for (int i = 0; i < 2; i++)
          #pragma unroll
          for (int j = 0; j < 4; j++){
            int n_l = wn*64 + j*16 + t16;
            int o_l0 = wm*32 + i*16 + quad*4;
            ushort4 pk = { f2bf(acc[i][j][0]), f2bf(acc[i][j][1]),
                           f2bf(acc[i][j][2]), f2bf(acc[i][j][3]) };
            *(ushort4*)(bsh + n_l*136 + o_l0) = pk;
          }
        asm volatile("s_waitcnt lgkmcnt(0)" ::: "memory");
        __builtin_amdgcn_s_barrier();
        unsigned short* dst = qn + (size_t)b * NTOK * DIM;
        #pragma unroll
        for (int p2 = 0; p2 < 4; p2++){
          int gg = t + p2 * 512;
          int n_l = gg >> 4, c = gg & 15;
          uint4 v = *(const uint4*)(bsh + n_l*136 + c*8);
          *(uint4*)(dst + (size_t)(n0 + n_l) * DIM + o0 + c*8) = v;
        }
      } else {
        #pragma unroll
        for (int i = 0; i < 2; i++)
          #pragma unroll
          for (int j = 0; j < 4; j++){
            int n_l = wn*64 + j*16 + t16;
            #pragma unroll
            for (int r = 0; r < 4; r++){
              int o_l = wm*32 + i*16 + quad*4 + r;
              bsh[o_l*136 + n_l] = f2bf(acc[i][j][r]);
            }
          }
        asm volatile("s_waitcnt lgkmcnt(0)" ::: "memory");
        __builtin_amdgcn_s_barrier();
        const int hl = w >> 2, dh = (w >> 1) & 1, eh = w & 1;
        const unsigned short* kbase = bsh + (hl*32 + dh*16) * 136;
        const unsigned short* vbase = bsh + (64 + hl*32 + eh*16) * 136;
        #pragma unroll
        for (int kk2 = 0; kk2 < 4; kk2++){
          int nn = kk2*32 + quad*8;
          short8 afrag = *(const short8*)(kbase + t16*136 + nn);
          short8 bfrag = *(const short8*)(vbase + t16*136 + nn);
          kvacc = __builtin_amdgcn_mfma_f32_16x16x32_bf16(afrag, bfrag, kvacc, 0, 0, 0);
        }
      }
      if (s == 3){
        #pragma unroll
        for (int i = 0; i < 2; i++)
          #pragma unroll
          for (int j = 0; j < 4; j++){ acc[i][j][0]=0.f; acc[i][j][1]=0.f; acc[i][j][2]=0.f; acc[i][j][3]=0.f; }
      }
    }
  }
#undef STAGE

  if (!isQ){
    const int pp = (o0 >> 7) - 2;          // head pair 0..3
    const int hl = w >> 2, dh = (w >> 1) & 1, eh = w & 1;
    float* dst = kvp + ((size_t)((b*8 + pp*2 + hl) * 16 + nt2)) * 1024;
    #pragma unroll
    for (int r = 0; r < 4; r++)
      dst[(dh*16 + quad*4 + r)*32 + eh*16 + t16] = kvacc[r];
  }
}

// ---------------- K3: reduce kv partials + fold Wproj: M[b][o][h*32+d] = sum_e Wp[o][h*32+e]*kv[d][e]
__global__ __launch_bounds__(256) void k_M(const float* __restrict__ kvp,
                                           const float* __restrict__ wproj,
                                           unsigned short* __restrict__ M){
  __shared__ float kvL[1024];
  __shared__ float wpL[8192];   // [o][e] 256x32
  const int t = threadIdx.x;
  const int h = blockIdx.x, b = blockIdx.y;
  const float* pbase = kvp + (size_t)((b*8 + h) * 16) * 1024;
  {
    float4 a = {0.f,0.f,0.f,0.f};
    #pragma unroll
    for (int p = 0; p < 16; p++){
      float4 v = *(const float4*)(pbase + (size_t)p*1024 + t*4);
      a.x += v.x; a.y += v.y; a.z += v.z; a.w += v.w;
    }
    *(float4*)(kvL + t*4) = a;
  }
  #pragma unroll
  for (int p = 0; p < 8; p++){
    int idx = t + p * 256;          // float4 index over 256x32
    int o = idx >> 3, e4 = idx & 7;
    *(float4*)(wpL + o*32 + e4*4) = *(const float4*)(wproj + (size_t)o * DIM + h*32 + e4*4);
  }
  __syncthreads();
  float wr[32];
  #pragma unroll
  for (int e = 0; e < 32; e++) wr[e] = wpL[t*32 + e];
  unsigned short md[32];
  #pragma unroll
  for (int d = 0; d < 32; d++){
    float a = 0.f;
    #pragma unroll
    for (int e = 0; e < 32; e++) a += wr[e] * kvL[d*32 + e];
    md[d] = f2bf(a);
  }
  unsigned short* dst = M + (size_t)b * 65536 + (size_t)t * DIM + h*32;
  #pragma unroll
  for (int q = 0; q < 4; q++) *(uint4*)(dst + q*8) = *(const uint4*)(md + q*8);
}

// ---------------- K4: out GEMM, 128o x 256n tile (512 blocks), FLIPPED operands ----------------
// A=qn n-rows (MFMA-A), B=M o-rows (MFMA-B): D row=n, col=o -> per-lane float4 along n.
// 2x the MFMA per staging drain vs k_out5 (32 vs 16 MFMA/wave/step at 6 vs 4 gloads).
__global__ __launch_bounds__(512, 2) void k_out6(const unsigned short* __restrict__ M,
                                                 const unsigned short* __restrict__ qn,
                                                 const float* __restrict__ x,
                                                 const float* __restrict__ bproj,
                                                 float* __restrict__ out){
  __shared__ __align__(16) unsigned short As[16384];  // qn: 256n x 64k (32 slabs)
  __shared__ __align__(16) unsigned short Bs[8192];   // M : 128o x 64k (16 slabs)
  const int t = threadIdx.x;
  const int w = t >> 6, l = t & 63;
  const int t16 = l & 15, quad = l >> 4;
  const int wm = w >> 1, wn = w & 1;     // wm 0..3: n-quarter (4 frags), wn 0..1: o-half (4 frags)
  // swizzle: 2 o-tiles sharing one (nt,b) within a 16-bid window
  const int bid = blockIdx.x;
  const int super = bid >> 4;            // 0..31
  const int rem = bid & 15;
  const int m = rem >> 3, lx = rem & 7;
  const int g = super * 8 + lx;          // 0..255
  const int nt = g >> 4, b = g & 15;
  const int o0 = m * 128, n0 = nt * 256;
  const unsigned short* A = qn + (size_t)b * NTOK * DIM;  // [n][256]
  const unsigned short* Bm = M + (size_t)b * 65536;       // [256][256]

  f32x4 acc[4][4];   // i over n (4x16), j over o (4x16)
  #pragma unroll
  for (int i = 0; i < 4; i++)
    #pragma unroll
    for (int j = 0; j < 4; j++){ acc[i][j][0]=0.f; acc[i][j][1]=0.f; acc[i][j][2]=0.f; acc[i][j][3]=0.f; }

  for (int k0 = 0; k0 < 256; k0 += 64){
    __syncthreads();
    // stage A (qn): 32 slabs, wave w does 4
    #pragma unroll
    for (int s4 = 0; s4 < 4; s4++){
      int sl = w*4 + s4;               // 0..31
      int tile = sl >> 1, kk = sl & 1;
      gload_lds16(A + (size_t)(n0 + tile*16 + t16) * DIM + k0 + kk*32 + quad*8, As + sl*512);
    }
    // stage B (M): 16 slabs, wave w does 2
    #pragma unroll
    for (int s2 = 0; s2 < 2; s2++){
      int sl = w*2 + s2;               // 0..15
      int tile = sl >> 1, kk = sl & 1;
      gload_lds16(Bm + (size_t)(o0 + tile*16 + t16) * DIM + k0 + kk*32 + quad*8, Bs + sl*512);
    }
    __syncthreads();
    #pragma unroll
    for (int kk = 0; kk < 2; kk++){
      short8 a[4], bb[4];
      #pragma unroll
      for (int i = 0; i < 4; i++) a[i]  = *(const short8*)(As + ((wm*4 + i)*2 + kk) * 512 + l * 8);
      #pragma unroll
      for (int j = 0; j < 4; j++) bb[j] = *(const short8*)(Bs + ((wn*4 + j)*2 + kk) * 512 + l * 8);
      #pragma unroll
      for (int i = 0; i < 4; i++)
        #pragma unroll
        for (int j = 0; j < 4; j++)
          acc[i][j] = __builtin_amdgcn_mfma_f32_16x16x32_bf16(a[i], bb[j], acc[i][j], 0, 0, 0);
    }
  }

  // epilogue: out[o][n] = acc + bias[o] + x[o][n], per-lane float4 along n
  const float* xb = x + (size_t)b * DIM * NTOK;
  float* ob = out + (size_t)b * DIM * NTOK;
  #pragma unroll
  for (int j = 0; j < 4; j++){
    int o = o0 + wn*64 + j*16 + t16;
    float bias = bproj[o];
    #pragma unroll
    for (int i = 0; i < 4; i++){
      int n = n0 + wm*64 + i*16 + quad*4;
      float4 xv = *(const float4*)(xb + (size_t)o * NTOK + n);
      float4 res = { acc[i][j][0] + bias + xv.x,
                     acc[i][j][1] + bias + xv.y,
                     acc[i][j][2] + bias + xv.z,
                     acc[i][j][3] + bias + xv.w };
      *(float4*)(ob + (size_t)o * NTOK + n) = res;
    }
  }
}

extern "C" void kernel_launch(void* const* d_in, const int* in_sizes, int n_in,
                              void* d_out, int out_size, void* d_ws, size_t ws_size,
                              hipStream_t stream){
  const float* x     = (const float*)d_in[0];
  const float* wqkv  = (const float*)d_in[1];
  const float* wproj = (const float*)d_in[2];
  const float* bproj = (const float*)d_in[3];
  float* out = (float*)d_out;
  char* ws = (char*)d_ws;

  // ws layout:
  unsigned short* xt   = (unsigned short*)(ws);                        // 32 MiB [b][n][256]
  unsigned short* qn   = (unsigned short*)(ws + ((size_t)32 << 20));   // 32 MiB [b][n][256]
  float* kvp           = (float*)(ws + ((size_t)64 << 20));            // 8 MiB [b][h][nt2 16][1024]
  unsigned short* M    = (unsigned short*)(ws + ((size_t)80 << 20));   // 2 MiB [b][256][256]
  unsigned short* wqbf = (unsigned short*)(ws + ((size_t)82 << 20));   // 384 KiB permuted

  k_prep  <<<dim3(64, 4, 17), 256, 0, stream>>>(x, xt, wqkv, wqbf);
  k_qkv11 <<<dim3(1536), 512, 0, stream>>>(wqbf, xt, qn, kvp);
  k_M     <<<dim3(8, 16), 256, 0, stream>>>(kvp, wproj, M);
  k_out6  <<<dim3(512), 512, 0, stream>>>(M, qn, x, bproj, out);
}

// Round 8
// 219.899 us; speedup vs baseline: 1.1111x; 1.0001x over previous
//
#include <hip/hip_runtime.h>
#include <stdint.h>
#include <stddef.h>

#define DIM   256
#define NH    8
#define HD    32
#define BATCH 16
#define NTOK  4096   // 64*64

typedef __attribute__((ext_vector_type(8))) short short8;
typedef __attribute__((ext_vector_type(4))) float f32x4;

__device__ __forceinline__ unsigned short f2bf(float x){
  unsigned u = __float_as_uint(x);
  u += 0x7fffu + ((u >> 16) & 1u);       // RNE
  return (unsigned short)(u >> 16);
}
__device__ __forceinline__ float elu1(float v){
  return (v > 0.f) ? (v + 1.f) : __expf(v);
}
// async global->LDS, 16B per lane. lds dest = wave-uniform base + lane*16.
__device__ __forceinline__ void gload_lds16(const void* g, void* lds){
  __builtin_amdgcn_global_load_lds(
      (const __attribute__((address_space(1))) unsigned int*)g,
      (__attribute__((address_space(3))) unsigned int*)lds, 16, 0, 0);
}

// ---------------- P1+P2 merged: transpose x AND convert Wqkv in one launch ----------------
__global__ __launch_bounds__(256) void k_prep(const float* __restrict__ x,
                                              unsigned short* __restrict__ xt,
                                              const float* __restrict__ wqkv,
                                              unsigned short* __restrict__ wq_bf){
  const int t = threadIdx.x;
  if (blockIdx.z < 16){
    __shared__ float tile[64][65];
    const int b = blockIdx.z, c0 = blockIdx.y * 64, n0 = blockIdx.x * 64;
    const float* xb = x + (size_t)b * DIM * NTOK;
    #pragma unroll
    for (int p = 0; p < 4; p++){
      int idx = t + p * 256;
      int row = idx >> 4;
      int col = (idx & 15) << 2;
      float4 v = *(const float4*)(xb + (size_t)(c0 + row) * NTOK + n0 + col);
      tile[row][col] = v.x; tile[row][col+1] = v.y; tile[row][col+2] = v.z; tile[row][col+3] = v.w;
    }
    __syncthreads();
    unsigned short* xtb = xt + (size_t)b * NTOK * DIM;
    #pragma unroll
    for (int p = 0; p < 4; p++){
      int idx = t + p * 256;
      int nl = idx >> 4;
      int cl = (idx & 15) << 2;
      ushort4 o;
      o.x = f2bf(tile[cl+0][nl]); o.y = f2bf(tile[cl+1][nl]);
      o.z = f2bf(tile[cl+2][nl]); o.w = f2bf(tile[cl+3][nl]);
      *(ushort4*)(xtb + (size_t)(n0 + nl) * DIM + c0 + cl) = o;
    }
  } else {
    const int blk = blockIdx.y * 64 + blockIdx.x;   // 0..255, use first 192
    if (blk >= 192) return;
    int i = blk * 256 + t;            // 49152 threads: 768 rows x 64 groups of 4c
    int row = i >> 6;
    int c4 = (i & 63) * 4;
    int dst;
    if (row < 256)      dst = row;
    else if (row < 512){ int p = (row - 256) >> 6; int s = (row - 256) & 63; dst = 256 + p*128 + s; }
    else               { int p = (row - 512) >> 6; int s = (row - 512) & 63; dst = 256 + p*128 + 64 + s; }
    float4 v = *(const float4*)(wqkv + (size_t)row * DIM + c4);
    ushort4 o = { f2bf(v.x), f2bf(v.y), f2bf(v.z), f2bf(v.w) };
    *(ushort4*)(wq_bf + (size_t)dst * DIM + c4) = o;
  }
}

// per-step staging: wave w stages A slabs w*4..+3 and B slabs w*4..+3 (8 gloads/thread)
__device__ __forceinline__ void stage_step(const unsigned short* __restrict__ A,
                                           const unsigned short* __restrict__ B,
                                           unsigned short* buf, int k0,
                                           int w, int t16, int quad){
  #pragma unroll
  for (int c = 0; c < 4; c++){
    int s = w*4 + c;                 // slab 0..31
    int f = s >> 1, kk = s & 1;      // frag row-group, k-half
    size_t off = (size_t)(f*16 + t16) * DIM + k0 + kk*32 + quad*8;
    gload_lds16(A + off, buf + s*512);
    gload_lds16(B + off, buf + 16384 + s*512);
  }
}

// ---------------- K1: qkv GEMM, 256x256 tile, 64 MFMA/wave per barrier-pair ----------------
// 768 blocks = 3 o-tiles x 256 chunks (b,nt). tile0 = q (rows 0..255); tile1/2 = two k|v pairs.
// K=256 in 4 steps of 64; 2x64KB LDS dbuf; counted vmcnt(8); stage(s+2) post-barrier into the
// just-freed buffer. Single fused epilogue at end reuses LDS as bounce [256][264] u16.
__global__ __launch_bounds__(512, 1) void k_qkv12(const unsigned short* __restrict__ wbf,
                                                  const unsigned short* __restrict__ xt,
                                                  unsigned short* __restrict__ qn,
                                                  float* __restrict__ kvp){
  __shared__ __align__(16) unsigned short sh[67584];  // staging 2x32768 u16; bounce 256x264 u16
  const int t = threadIdx.x;
  const int w = t >> 6, l = t & 63;
  const int t16 = l & 15, quad = l >> 4;
  const int wm = w >> 2, wn = w & 3;     // wm 0..1 (o-half 128), wn 0..3 (n-quarter 64)
  // swizzle: 3 o-tiles of one chunk inside a 24-bid window (same XCD for xt reuse)
  const int bid = blockIdx.x;
  const int super = bid / 24;            // 0..31
  const int rem = bid - super * 24;
  const int m = rem >> 3, lx = rem & 7;  // m 0..2
  const int chunk = super * 8 + lx;      // 0..255
  const int b = chunk >> 4, nt = chunk & 15;
  const int o0 = m * 256, n0 = nt * 256;
  const bool isQ = (m == 0);
  const unsigned short* A = wbf + (size_t)o0 * DIM;
  const unsigned short* B = xt + ((size_t)b * NTOK + n0) * DIM;

  stage_step(A, B, sh,         0, w, t16, quad);   // step 0 -> buf0
  stage_step(A, B, sh + 32768, 64, w, t16, quad);  // step 1 -> buf1

  f32x4 acc[8][4];   // i over o (8x16), j over n (4x16)
  #pragma unroll
  for (int i = 0; i < 8; i++)
    #pragma unroll
    for (int j = 0; j < 4; j++){ acc[i][j][0]=0.f; acc[i][j][1]=0.f; acc[i][j][2]=0.f; acc[i][j][3]=0.f; }

  #pragma unroll
  for (int s = 0; s < 4; s++){
    if (s < 3) { asm volatile("s_waitcnt vmcnt(8)" ::: "memory"); }
    else       { asm volatile("s_waitcnt vmcnt(0)" ::: "memory"); }
    __builtin_amdgcn_s_barrier();                   // all waves' stage(s) complete
    const unsigned short* buf = sh + (s & 1) * 32768;
    #pragma unroll
    for (int kk = 0; kk < 2; kk++){
      short8 av[8], bv[4];
      #pragma unroll
      for (int i = 0; i < 8; i++) av[i] = *(const short8*)(buf + ((wm*8 + i)*2 + kk)*512 + l*8);
      #pragma unroll
      for (int j = 0; j < 4; j++) bv[j] = *(const short8*)(buf + 16384 + ((wn*4 + j)*2 + kk)*512 + l*8);
      #pragma unroll
      for (int i = 0; i < 8; i++)
        #pragma unroll
        for (int j = 0; j < 4; j++)
          acc[i][j] = __builtin_amdgcn_mfma_f32_16x16x32_bf16(av[i], bv[j], acc[i][j], 0, 0, 0);
    }
    __builtin_amdgcn_s_barrier();                   // all waves consumed buf[s&1]
    if (s < 2) stage_step(A, B, sh + (s & 1)*32768, (s + 2)*64, w, t16, quad);
  }
  // epilogue: reuse all of sh as bounce [row][264] u16 (stride 264 == 136-equiv banking)
  unsigned short* bsh = sh;

  if (isQ){
    // elu + per-head (32-row) normalize, all 8 o-frags
    #pragma unroll
    for (int i = 0; i < 8; i++)
      #pragma unroll
      for (int j = 0; j < 4; j++)
        #pragma unroll
        for (int r = 0; r < 4; r++) acc[i][j][r] = elu1(acc[i][j][r]);
    #pragma unroll
    for (int hh = 0; hh < 4; hh++)
      #pragma unroll
      for (int j = 0; j < 4; j++){
        float v = 0.f;
        #pragma unroll
        for (int ii = 0; ii < 2; ii++)
          #pragma unroll
          for (int r = 0; r < 4; r++) v += acc[hh*2 + ii][j][r];
        v += __shfl_xor(v, 16);
        v += __shfl_xor(v, 32);
        float inv = 1.0f / v;
        #pragma unroll
        for (int ii = 0; ii < 2; ii++)
          #pragma unroll
          for (int r = 0; r < 4; r++) acc[hh*2 + ii][j][r] *= inv;
      }
    // bounce [n 256][o 264-stride], packed ushort4 along o
    #pragma unroll
    for (int i = 0; i < 8; i++)
      #pragma unroll
      for (int j = 0; j < 4; j++){
        int n_l = wn*64 + j*16 + t16;
        int o_l0 = wm*128 + i*16 + quad*4;
        ushort4 pk = { f2bf(acc[i][j][0]), f2bf(acc[i][j][1]),
                       f2bf(acc[i][j][2]), f2bf(acc[i][j][3]) };
        *(ushort4*)(bsh + n_l*264 + o_l0) = pk;
      }
    asm volatile("s_waitcnt lgkmcnt(0)" ::: "memory");
    __builtin_amdgcn_s_barrier();
    unsigned short* dst = qn + (size_t)b * NTOK * DIM;
    #pragma unroll
    for (int p2 = 0; p2 < 16; p2++){
      int idx = t + p2 * 512;          // 8192 16B-chunks: 256 n x 32 chunks
      int n_l = idx >> 5, c16 = idx & 31;
      uint4 v = *(const uint4*)(bsh + n_l*264 + c16*8);
      *(uint4*)(dst + (size_t)(n0 + n_l) * DIM + c16*8) = v;
    }
  } else {
    // k rows = i 0..3 of each wave's pair (wm): elu + normalize per head (hh 0..1)
    #pragma unroll
    for (int i = 0; i < 4; i++)
      #pragma unroll
      for (int j = 0; j < 4; j++)
        #pragma unroll
        for (int r = 0; r < 4; r++) acc[i][j][r] = elu1(acc[i][j][r]);
    #pragma unroll
    for (int hh = 0; hh < 2; hh++)
      #pragma unroll
      for (int j = 0; j < 4; j++){
        float v = 0.f;
        #pragma unroll
        for (int ii = 0; ii < 2; ii++)
          #pragma unroll
          for (int r = 0; r < 4; r++) v += acc[hh*2 + ii][j][r];
        v += __shfl_xor(v, 16);
        v += __shfl_xor(v, 32);
        float inv = 1.0f / v;
        #pragma unroll
        for (int ii = 0; ii < 2; ii++)
          #pragma unroll
          for (int r = 0; r < 4; r++) acc[hh*2 + ii][j][r] *= inv;
      }
    // bounce [o 256][n 264-stride] (n-contiguous rows for kv MFMA)
    #pragma unroll
    for (int i = 0; i < 8; i++)
      #pragma unroll
      for (int j = 0; j < 4; j++){
        int n_l = wn*64 + j*16 + t16;
        #pragma unroll
        for (int r = 0; r < 4; r++){
          int o_l = wm*128 + i*16 + quad*4 + r;
          bsh[o_l*264 + n_l] = f2bf(acc[i][j][r]);
        }
      }
    asm volatile("s_waitcnt lgkmcnt(0)" ::: "memory");
    __builtin_amdgcn_s_barrier();
    // kv partials over 256 tokens: 16 tasks (q,hl,dh,eh); wave w does tasks w and w+8
    #pragma unroll
    for (int task = 0; task < 2; task++){
      const int tt = w + task*8;
      const int q = tt >> 3, hl = (tt >> 2) & 1, dh = (tt >> 1) & 1, eh = tt & 1;
      f32x4 kvacc;
      kvacc[0]=0.f; kvacc[1]=0.f; kvacc[2]=0.f; kvacc[3]=0.f;
      const unsigned short* kbase = bsh + (q*128 + hl*32 + dh*16 + t16) * 264;       // normalized k
      const unsigned short* vbase = bsh + (q*128 + 64 + hl*32 + eh*16 + t16) * 264;  // raw v
      #pragma unroll
      for (int kk2 = 0; kk2 < 8; kk2++){
        int nn = kk2*32 + quad*8;
        short8 afrag = *(const short8*)(kbase + nn);
        short8 bfrag = *(const short8*)(vbase + nn);
        kvacc = __builtin_amdgcn_mfma_f32_16x16x32_bf16(afrag, bfrag, kvacc, 0, 0, 0);
      }
      const int pp_g = (m - 1)*2 + q;   // global head-pair 0..3
      float* dst = kvp + ((size_t)((b*8 + pp_g*2 + hl) * 16 + nt)) * 1024;
      #pragma unroll
      for (int r = 0; r < 4; r++)
        dst[(dh*16 + quad*4 + r)*32 + eh*16 + t16] = kvacc[r];
    }
  }
}

// ---------------- K3: reduce kv partials + fold Wproj: M[b][o][h*32+d] = sum_e Wp[o][h*32+e]*kv[d][e]
__global__ __launch_bounds__(256) void k_M(const float* __restrict__ kvp,
                                           const float* __restrict__ wproj,
                                           unsigned short* __restrict__ M){
  __shared__ float kvL[1024];
  __shared__ float wpL[8192];   // [o][e] 256x32
  const int t = threadIdx.x;
  const int h = blockIdx.x, b = blockIdx.y;
  const float* pbase = kvp + (size_t)((b*8 + h) * 16) * 1024;
  {
    float4 a = {0.f,0.f,0.f,0.f};
    #pragma unroll
    for (int p = 0; p < 16; p++){
      float4 v = *(const float4*)(pbase + (size_t)p*1024 + t*4);
      a.x += v.x; a.y += v.y; a.z += v.z; a.w += v.w;
    }
    *(float4*)(kvL + t*4) = a;
  }
  #pragma unroll
  for (int p = 0; p < 8; p++){
    int idx = t + p * 256;          // float4 index over 256x32
    int o = idx >> 3, e4 = idx & 7;
    *(float4*)(wpL + o*32 + e4*4) = *(const float4*)(wproj + (size_t)o * DIM + h*32 + e4*4);
  }
  __syncthreads();
  float wr[32];
  #pragma unroll
  for (int e = 0; e < 32; e++) wr[e] = wpL[t*32 + e];
  unsigned short md[32];
  #pragma unroll
  for (int d = 0; d < 32; d++){
    float a = 0.f;
    #pragma unroll
    for (int e = 0; e < 32; e++) a += wr[e] * kvL[d*32 + e];
    md[d] = f2bf(a);
  }
  unsigned short* dst = M + (size_t)b * 65536 + (size_t)t * DIM + h*32;
  #pragma unroll
  for (int q = 0; q < 4; q++) *(uint4*)(dst + q*8) = *(const uint4*)(md + q*8);
}

// ---------------- K4: out GEMM, 128o x 256n tile (512 blocks), FLIPPED operands ----------------
__global__ __launch_bounds__(512, 2) void k_out6(const unsigned short* __restrict__ M,
                                                 const unsigned short* __restrict__ qn,
                                                 const float* __restrict__ x,
                                                 const float* __restrict__ bproj,
                                                 float* __restrict__ out){
  __shared__ __align__(16) unsigned short As[16384];  // qn: 256n x 64k (32 slabs)
  __shared__ __align__(16) unsigned short Bs[8192];   // M : 128o x 64k (16 slabs)
  const int t = threadIdx.x;
  const int w = t >> 6, l = t & 63;
  const int t16 = l & 15, quad = l >> 4;
  const int wm = w >> 1, wn = w & 1;     // wm 0..3: n-quarter, wn 0..1: o-half
  const int bid = blockIdx.x;
  const int super = bid >> 4;            // 0..31
  const int rem = bid & 15;
  const int m = rem >> 3, lx = rem & 7;
  const int g = super * 8 + lx;          // 0..255
  const int nt = g >> 4, b = g & 15;
  const int o0 = m * 128, n0 = nt * 256;
  const unsigned short* A = qn + (size_t)b * NTOK * DIM;  // [n][256]
  const unsigned short* Bm = M + (size_t)b * 65536;       // [256][256]

  f32x4 acc[4][4];   // i over n (4x16), j over o (4x16)
  #pragma unroll
  for (int i = 0; i < 4; i++)
    #pragma unroll
    for (int j = 0; j < 4; j++){ acc[i][j][0]=0.f; acc[i][j][1]=0.f; acc[i][j][2]=0.f; acc[i][j][3]=0.f; }

  for (int k0 = 0; k0 < 256; k0 += 64){
    __syncthreads();
    #pragma unroll
    for (int s4 = 0; s4 < 4; s4++){
      int sl = w*4 + s4;               // 0..31
      int tile = sl >> 1, kk = sl & 1;
      gload_lds16(A + (size_t)(n0 + tile*16 + t16) * DIM + k0 + kk*32 + quad*8, As + sl*512);
    }
    #pragma unroll
    for (int s2 = 0; s2 < 2; s2++){
      int sl = w*2 + s2;               // 0..15
      int tile = sl >> 1, kk = sl & 1;
      gload_lds16(Bm + (size_t)(o0 + tile*16 + t16) * DIM + k0 + kk*32 + quad*8, Bs + sl*512);
    }
    __syncthreads();
    #pragma unroll
    for (int kk = 0; kk < 2; kk++){
      short8 a[4], bb[4];
      #pragma unroll
      for (int i = 0; i < 4; i++) a[i]  = *(const short8*)(As + ((wm*4 + i)*2 + kk) * 512 + l * 8);
      #pragma unroll
      for (int j = 0; j < 4; j++) bb[j] = *(const short8*)(Bs + ((wn*4 + j)*2 + kk) * 512 + l * 8);
      #pragma unroll
      for (int i = 0; i < 4; i++)
        #pragma unroll
        for (int j = 0; j < 4; j++)
          acc[i][j] = __builtin_amdgcn_mfma_f32_16x16x32_bf16(a[i], bb[j], acc[i][j], 0, 0, 0);
    }
  }

  const float* xb = x + (size_t)b * DIM * NTOK;
  float* ob = out + (size_t)b * DIM * NTOK;
  #pragma unroll
  for (int j = 0; j < 4; j++){
    int o = o0 + wn*64 + j*16 + t16;
    float bias = bproj[o];
    #pragma unroll
    for (int i = 0; i < 4; i++){
      int n = n0 + wm*64 + i*16 + quad*4;
      float4 xv = *(const float4*)(xb + (size_t)o * NTOK + n);
      float4 res = { acc[i][j][0] + bias + xv.x,
                     acc[i][j][1] + bias + xv.y,
                     acc[i][j][2] + bias + xv.z,
                     acc[i][j][3] + bias + xv.w };
      *(float4*)(ob + (size_t)o * NTOK + n) = res;
    }
  }
}

extern "C" void kernel_launch(void* const* d_in, const int* in_sizes, int n_in,
                              void* d_out, int out_size, void* d_ws, size_t ws_size,
                              hipStream_t stream){
  const float* x     = (const float*)d_in[0];
  const float* wqkv  = (const float*)d_in[1];
  const float* wproj = (const float*)d_in[2];
  const float* bproj = (const float*)d_in[3];
  float* out = (float*)d_out;
  char* ws = (char*)d_ws;

  // ws layout:
  unsigned short* xt   = (unsigned short*)(ws);                        // 32 MiB [b][n][256]
  unsigned short* qn   = (unsigned short*)(ws + ((size_t)32 << 20));   // 32 MiB [b][n][256]
  float* kvp           = (float*)(ws + ((size_t)64 << 20));            // 8 MiB [b][h][nt 16][1024]
  unsigned short* M    = (unsigned short*)(ws + ((size_t)80 << 20));   // 2 MiB [b][256][256]
  unsigned short* wqbf = (unsigned short*)(ws + ((size_t)82 << 20));   // 384 KiB permuted

  k_prep  <<<dim3(64, 4, 17), 256, 0, stream>>>(x, xt, wqkv, wqbf);
  k_qkv12 <<<dim3(768), 512, 0, stream>>>(wqbf, xt, qn, kvp);
  k_M     <<<dim3(8, 16), 256, 0, stream>>>(kvp, wproj, M);
  k_out6  <<<dim3(512), 512, 0, stream>>>(M, qn, x, bproj, out);
}